// Round 12
// baseline (10.746 us; speedup 1.0000x reference)
//
#include <hip/hip_runtime.h>

constexpr int Hc = 512, Wc = 512;
constexpr int HWc = Hc * Wc;          // 262144
constexpr int NP  = 4 * HWc;          // 1048576 pixels (B,H,W)

typedef float vf4 __attribute__((ext_vector_type(4)));   // clang-native for nontemporal

// Closed-form TV-L1 (p-term dropped; justified round 9, validated rounds 9-10):
//   T = clamp(I1-I0, -15*theta*lam*ng, +15*theta*lam*ng); u = -g*T/ng
// 8 px/thread, float4 loads, non-temporal stores (u is write-once).
__device__ __forceinline__ void ldrow10(const float* __restrict__ I, int h, int w0,
                                        float r[10]) {
  if (h < 0 || h >= Hc) {
    #pragma unroll
    for (int k = 0; k < 10; ++k) r[k] = 0.f;
    return;
  }
  const float* row = I + h * Wc;
  vf4 c0 = *reinterpret_cast<const vf4*>(row + w0);       // 16B aligned
  vf4 c1 = *reinterpret_cast<const vf4*>(row + w0 + 4);
  r[0] = (w0 > 0) ? row[w0 - 1] : 0.f;
  r[1] = c0.x; r[2] = c0.y; r[3] = c0.z; r[4] = c0.w;
  r[5] = c1.x; r[6] = c1.y; r[7] = c1.z; r[8] = c1.w;
  r[9] = (w0 + 8 < Wc) ? row[w0 + 8] : 0.f;
}

__global__ void __launch_bounds__(256)
k_tvl1(const float* __restrict__ x, float* __restrict__ uOut,
       const float* __restrict__ lamp, const float* __restrict__ thetap) {
  int idx = blockIdx.x * 256 + threadIdx.x;   // NP/8 = 131072 threads, 8 px each
  int w0 = (idx & 63) << 3;                   // 64 threads span one 512-px row
  int h  = (idx >> 6) & (Hc - 1);
  int b  = idx >> 15;

  const float* I0 = x + (b * 2 + 0) * HWc;
  const float* I1 = x + (b * 2 + 1) * HWc;
  const float tl15 = 15.f * thetap[0] * lamp[0];

  float rm[10], rcn[10], rp[10];
  ldrow10(I1, h - 1, w0, rm);
  ldrow10(I1, h,     w0, rcn);
  ldrow10(I1, h + 1, w0, rp);
  const float* I0r = I0 + h * Wc + w0;
  vf4 i0a = *reinterpret_cast<const vf4*>(I0r);
  vf4 i0b = *reinterpret_cast<const vf4*>(I0r + 4);
  float i0v[8] = { i0a.x, i0a.y, i0a.z, i0a.w, i0b.x, i0b.y, i0b.z, i0b.w };

  float u0[8], u1[8];
  #pragma unroll
  for (int j = 0; j < 8; ++j) {
    float gx = (rm[j] - rm[j + 2]) + 2.f * (rcn[j] - rcn[j + 2]) + (rp[j] - rp[j + 2]);
    float gy = (rm[j] + 2.f * rm[j + 1] + rm[j + 2]) - (rp[j] + 2.f * rp[j + 1] + rp[j + 2]);
    float ng = gx * gx + gy * gy;
    float z  = rcn[j + 1] - i0v[j];
    float m15 = tl15 * ng;
    float tm = fminf(fmaxf(z, -m15), m15);
    float q  = (ng > 0.f) ? (tm / ng) : 0.f;
    u0[j] = -q * gx;
    u1[j] = -q * gy;
  }

  float* U0o = uOut + b * 2 * HWc + h * Wc + w0;
  vf4 s0 = { u0[0], u0[1], u0[2], u0[3] };
  vf4 s1 = { u0[4], u0[5], u0[6], u0[7] };
  vf4 s2 = { u1[0], u1[1], u1[2], u1[3] };
  vf4 s3 = { u1[4], u1[5], u1[6], u1[7] };
  __builtin_nontemporal_store(s0, reinterpret_cast<vf4*>(U0o));
  __builtin_nontemporal_store(s1, reinterpret_cast<vf4*>(U0o + 4));
  __builtin_nontemporal_store(s2, reinterpret_cast<vf4*>(U0o + HWc));
  __builtin_nontemporal_store(s3, reinterpret_cast<vf4*>(U0o + HWc + 4));
}

extern "C" void kernel_launch(void* const* d_in, const int* in_sizes, int n_in,
                              void* d_out, int out_size, void* d_ws, size_t ws_size,
                              hipStream_t stream) {
  const float* x     = (const float*)d_in[0];
  const float* lam   = (const float*)d_in[3];
  const float* theta = (const float*)d_in[5];
  float* uOut = (float*)d_out;
  k_tvl1<<<NP / 8 / 256, 256, 0, stream>>>(x, uOut, lam, theta);
}